// Round 3
// baseline (1738.200 us; speedup 1.0000x reference)
//
#include <hip/hip_runtime.h>
#include <math.h>

#define Z 512
#define XV 10000
#define SEQ 256
#define NB 64
#define JS 128                 // j-slice width per block (K=4 slices)
#define AGENT __HIP_MEMORY_SCOPE_AGENT

typedef _Float16 h2t __attribute__((ext_vector_type(2)));

__device__ __forceinline__ float dot2f(unsigned a, unsigned b, float c) {
#if __has_builtin(__builtin_amdgcn_fdot2)
    return __builtin_amdgcn_fdot2(__builtin_bit_cast(h2t, a), __builtin_bit_cast(h2t, b), c, false);
#else
    h2t av = __builtin_bit_cast(h2t, a), bv = __builtin_bit_cast(h2t, b);
    return fmaf((float)av[0], (float)bv[0], fmaf((float)av[1], (float)bv[1], c));
#endif
}

__device__ __forceinline__ unsigned pack_h2(float a, float b) {
    h2t v; v[0] = (_Float16)a; v[1] = (_Float16)b;
    return __builtin_bit_cast(unsigned, v);
}

__device__ __forceinline__ void online_combine(float& m, float& s, float pm, float ps) {
    if (pm > m) { s = s * __expf(m - pm) + ps; m = pm; }
    else        { s = s + ps * __expf(pm - m); }
}

// ---------------- prep kernels (unchanged from round 2) ----------------
__global__ void k_t_collse(const float* __restrict__ T, float* __restrict__ colLSE) {
    __shared__ float ms[256], ss[256];
    const int tid = threadIdx.x;
    const int c0 = blockIdx.x * 64;
    const int cl = tid & 63;
    const int r0 = tid >> 6;
    const int c  = c0 + cl;
    float m = -INFINITY, s = 0.f;
    for (int r = r0; r < Z; r += 4)
        online_combine(m, s, T[(size_t)r * Z + c], 1.f);
    ms[tid] = m; ss[tid] = s;
    __syncthreads();
    if (tid < 128) {
        m = ms[tid]; s = ss[tid];
        online_combine(m, s, ms[tid + 128], ss[tid + 128]);
        ms[tid] = m; ss[tid] = s;
    }
    __syncthreads();
    if (tid < 64) {
        m = ms[tid]; s = ss[tid];
        online_combine(m, s, ms[tid + 64], ss[tid + 64]);
        colLSE[c0 + tid] = m + __logf(s);
    }
}

__global__ void k_emit_part(const float* __restrict__ emit, float2* __restrict__ part) {
    __shared__ float ms[256], ss[256];
    const int tid = threadIdx.x;
    const int g  = blockIdx.x & 7;
    const int rg = blockIdx.x >> 3;
    const int cl = tid & 63;
    const int r0 = tid >> 6;
    const int c  = g * 64 + cl;
    const int rstart = rg * 313;
    const int rend   = (rstart + 313 < XV) ? rstart + 313 : XV;
    float m = -INFINITY, s = 0.f;
    for (int r = rstart + r0; r < rend; r += 4)
        online_combine(m, s, emit[(size_t)r * Z + c], 1.f);
    ms[tid] = m; ss[tid] = s;
    __syncthreads();
    if (tid < 128) {
        m = ms[tid]; s = ss[tid];
        online_combine(m, s, ms[tid + 128], ss[tid + 128]);
        ms[tid] = m; ss[tid] = s;
    }
    __syncthreads();
    if (tid < 64) {
        m = ms[tid]; s = ss[tid];
        online_combine(m, s, ms[tid + 64], ss[tid + 64]);
        part[(size_t)rg * Z + g * 64 + tid] = make_float2(m, s);
    }
}

__global__ void k_finalize(const float2* __restrict__ part, const float* __restrict__ pi,
                           float* __restrict__ emit_lse, float* __restrict__ pi_eff) {
    __shared__ float sm[512];
    const int z = threadIdx.x;
    float m = -INFINITY, s = 0.f;
    for (int rg = 0; rg < 32; ++rg) {
        float2 p = part[(size_t)rg * Z + z];
        online_combine(m, s, p.x, p.y);
    }
    const float el = m + __logf(s);
    emit_lse[z] = el;
    const float v = pi[z];
    sm[z] = v; __syncthreads();
    for (int off = 256; off > 0; off >>= 1) {
        if (z < off) sm[z] = fmaxf(sm[z], sm[z + off]);
        __syncthreads();
    }
    const float mx = sm[0];
    __syncthreads();
    sm[z] = __expf(v - mx); __syncthreads();
    for (int off = 256; off > 0; off >>= 1) {
        if (z < off) sm[z] += sm[z + off];
        __syncthreads();
    }
    const float lse_pi = mx + __logf(sm[0]);
    pi_eff[z] = (v - lse_pi) - el;
}

// M dword(k, j) = half2(E[2k][j], E[2k+1][j]),  E[i][j] = exp(T_log[j][i] - mT[j])
__global__ void k_build_ET(const float* __restrict__ T, const float* __restrict__ colLSE,
                           const float* __restrict__ emit_lse,
                           _Float16* __restrict__ H, float* __restrict__ adj) {
    __shared__ float sm[256];
    const int j = blockIdx.x, t = threadIdx.x;
    const float v0 = T[(size_t)j * Z + t]       - colLSE[t];
    const float v1 = T[(size_t)j * Z + t + 256] - colLSE[t + 256];
    float m = fmaxf(v0, v1);
    sm[t] = m; __syncthreads();
    for (int off = 128; off > 0; off >>= 1) {
        if (t < off) sm[t] = fmaxf(sm[t], sm[t + off]);
        __syncthreads();
    }
    const float mT = sm[0];
    H[(size_t)(t >> 1) * 1024 + 2 * j + (t & 1)]         = (_Float16)__expf(v0 - mT);
    H[(size_t)((t + 256) >> 1) * 1024 + 2 * j + (t & 1)] = (_Float16)__expf(v1 - mT);
    if (t == 0) adj[j] = mT - emit_lse[j];
}

// ---------------- the scan: 256 blocks = 64 batches x 4 j-slices ----------------
// LDS-resident M slice (128 KB, XOR-swizzled). Per-step cross-slice alpha exchange
// via device-scope flags + double-buffered global alpha.
__global__ void __launch_bounds__(1024, 4)
k_hmm_scan(const int* __restrict__ ids, const float* __restrict__ emit,
           const unsigned* __restrict__ Mbuf, const float* __restrict__ adj,
           const float* __restrict__ pi_eff,
           float* __restrict__ bufA, float* __restrict__ bufM,
           unsigned* __restrict__ flags, float* __restrict__ out) {
    extern __shared__ unsigned lds_m[];          // [128 jj][256 k] dwords, k4 XOR-swizzled
    __shared__ unsigned ea2u[Z / 2];
    __shared__ float sred[8][JS];
    __shared__ float redm4[4], redm2[2], sfin[8];

    const int b  = blockIdx.x & 63;
    const int k  = blockIdx.x >> 6;              // slice id 0..3
    const int js = k * JS;
    const int tid = threadIdx.x;
    const int jj = tid & 127;
    const int h  = tid >> 7;                     // 0..7, i-range owner

    // stage M slice -> LDS (one-time). global dword(kk, js+jj), coalesced per wave.
    for (int it = 0; it < 32; ++it) {
        const int kk = it * 8 + h;               // 0..255
        const unsigned v = Mbuf[(size_t)kk * Z + js + jj];
        lds_m[jj * 256 + ((((kk >> 2) ^ (jj & 7)) << 2) | (kk & 3))] = v;
    }

    float adjj = 0.f, alpha = 0.f;
    if (tid < JS) {
        adjj = adj[js + tid];
        alpha = emit[(size_t)ids[b] * Z + js + tid] + pi_eff[js + tid];
    }

    // publish alpha0 -> buffer 0, flag = 1
    {
        float mv = (tid < JS) ? alpha : -INFINITY;
        if (tid < JS)
            __hip_atomic_store(bufA + (size_t)b * Z + js + tid, alpha, __ATOMIC_RELAXED, AGENT);
        #pragma unroll
        for (int off = 32; off > 0; off >>= 1) mv = fmaxf(mv, __shfl_xor(mv, off));
        if (tid < JS && (tid & 63) == 0) redm2[tid >> 6] = mv;
        __syncthreads();                         // drains the atomic stores too
        if (tid == 0) {
            __hip_atomic_store(bufM + b * 4 + k, fmaxf(redm2[0], redm2[1]), __ATOMIC_RELAXED, AGENT);
            __hip_atomic_store(flags + b * 4 + k, 1u, __ATOMIC_RELEASE, AGENT);
        }
    }

    for (int t = 1; t < SEQ; ++t) {
        const int id = ids[t * NB + b];
        float obs = 0.f;
        if (tid < JS) obs = emit[(size_t)id * Z + js + tid];   // issued before the wait

        const int par = (t - 1) & 1;
        if (tid < 4) {
            const unsigned want = (unsigned)t;
            while (__hip_atomic_load(flags + b * 4 + tid, __ATOMIC_RELAXED, AGENT) < want)
                __builtin_amdgcn_s_sleep(2);
            (void)__hip_atomic_load(flags + b * 4 + tid, __ATOMIC_ACQUIRE, AGENT);
            redm4[tid] = __hip_atomic_load(bufM + (par * 64 + b) * 4 + tid, __ATOMIC_RELAXED, AGENT);
        }
        __syncthreads();                                       // B1
        const float m_a = fmaxf(fmaxf(redm4[0], redm4[1]), fmaxf(redm4[2], redm4[3]));
        if (tid < Z) {
            const float av = __hip_atomic_load(bufA + (size_t)(par * 64 + b) * Z + tid,
                                               __ATOMIC_RELAXED, AGENT);
            const float e = __expf(av - m_a);
            const float eo = __shfl_xor(e, 1);
            if (!(tid & 1)) ea2u[tid >> 1] = pack_h2(e, eo);
        }
        __syncthreads();                                       // B2

        float s0 = 0.f, s1 = 0.f, s2 = 0.f, s3 = 0.f;
        const int base = jj * 256;
        #pragma unroll
        for (int k4 = 8 * h; k4 < 8 * h + 8; ++k4) {
            const uint4 m  = *(const uint4*)(lds_m + base + ((k4 ^ (jj & 7)) << 2));
            const uint4 ea = *(const uint4*)(ea2u + (k4 << 2));
            s0 = dot2f(ea.x, m.x, s0);
            s1 = dot2f(ea.y, m.y, s1);
            s2 = dot2f(ea.z, m.z, s2);
            s3 = dot2f(ea.w, m.w, s3);
        }
        sred[h][jj] = (s0 + s1) + (s2 + s3);
        __syncthreads();                                       // B3

        const int cur = t & 1;
        float mv = -INFINITY;
        if (tid < JS) {
            float s = 0.f;
            #pragma unroll
            for (int hh = 0; hh < 8; ++hh) s += sred[hh][tid];
            alpha = obs + adjj + m_a + __logf(s);
            __hip_atomic_store(bufA + (size_t)(cur * 64 + b) * Z + js + tid, alpha,
                               __ATOMIC_RELAXED, AGENT);
            mv = alpha;
        }
        #pragma unroll
        for (int off = 32; off > 0; off >>= 1) mv = fmaxf(mv, __shfl_xor(mv, off));
        if (tid < JS && (tid & 63) == 0) redm2[tid >> 6] = mv;
        __syncthreads();                                       // B4 (drains bufA stores)
        if (tid == 0) {
            __hip_atomic_store(bufM + (cur * 64 + b) * 4 + k, fmaxf(redm2[0], redm2[1]),
                               __ATOMIC_RELAXED, AGENT);
            __hip_atomic_store(flags + b * 4 + k, (unsigned)(t + 1), __ATOMIC_RELEASE, AGENT);
        }
    }

    // final: wait for flag 256, LSE over full alpha_{255} (buffer parity 1)
    if (tid < 4) {
        while (__hip_atomic_load(flags + b * 4 + tid, __ATOMIC_RELAXED, AGENT) < (unsigned)SEQ)
            __builtin_amdgcn_s_sleep(2);
        (void)__hip_atomic_load(flags + b * 4 + tid, __ATOMIC_ACQUIRE, AGENT);
        redm4[tid] = __hip_atomic_load(bufM + (64 + b) * 4 + tid, __ATOMIC_RELAXED, AGENT);
    }
    __syncthreads();
    const float m_f = fmaxf(fmaxf(redm4[0], redm4[1]), fmaxf(redm4[2], redm4[3]));
    float ev = 0.f;
    if (tid < Z)
        ev = __expf(__hip_atomic_load(bufA + (size_t)(64 + b) * Z + tid,
                                      __ATOMIC_RELAXED, AGENT) - m_f);
    #pragma unroll
    for (int off = 32; off > 0; off >>= 1) ev += __shfl_xor(ev, off);
    if (tid < Z && (tid & 63) == 0) sfin[tid >> 6] = ev;
    __syncthreads();
    if (k == 0 && tid == 0) {
        float tot = 0.f;
        #pragma unroll
        for (int q = 0; q < 8; ++q) tot += sfin[q];
        out[b] = -(m_f + __logf(tot));
    }
}

extern "C" void kernel_launch(void* const* d_in, const int* in_sizes, int n_in,
                              void* d_out, int out_size, void* d_ws, size_t ws_size,
                              hipStream_t stream) {
    const int*   ids  = (const int*)d_in[0];    // [256,64]
    const float* T    = (const float*)d_in[1];  // [512,512]
    const float* pi   = (const float*)d_in[2];  // [512]
    const float* emit = (const float*)d_in[3];  // [10000,512]
    float* out = (float*)d_out;                 // [64]

    float* wsf = (float*)d_ws;
    unsigned* Mbuf   = (unsigned*)wsf;          // 131072 dw = 512 KB fp16 M
    float*  colLSE   = wsf + 131072;
    float*  adj      = wsf + 131584;
    float*  pi_eff   = wsf + 132096;
    float*  emit_lse = wsf + 132608;
    float2* em_part  = (float2*)(wsf + 133120); // 32768 floats
    float*  bufA     = wsf + 165888;            // [2][64][512] = 65536 floats
    float*  bufM     = wsf + 231424;            // [2][64][4]   = 512 floats
    unsigned* flags  = (unsigned*)(wsf + 231936); // [64][4]

    hipLaunchKernelGGL(k_t_collse,  dim3(8),   dim3(256), 0, stream, T, colLSE);
    hipLaunchKernelGGL(k_emit_part, dim3(256), dim3(256), 0, stream, emit, em_part);
    hipLaunchKernelGGL(k_finalize,  dim3(1),   dim3(512), 0, stream, em_part, pi, emit_lse, pi_eff);
    hipLaunchKernelGGL(k_build_ET,  dim3(512), dim3(256), 0, stream, T, colLSE, emit_lse,
                       (_Float16*)Mbuf, adj);

    hipMemsetAsync(flags, 0, 64 * 4 * sizeof(unsigned), stream);

    hipFuncSetAttribute((const void*)k_hmm_scan,
                        hipFuncAttributeMaxDynamicSharedMemorySize, 131072);
    void* args[] = { (void*)&ids, (void*)&emit, (void*)&Mbuf, (void*)&adj, (void*)&pi_eff,
                     (void*)&bufA, (void*)&bufM, (void*)&flags, (void*)&out };
    hipLaunchCooperativeKernel((const void*)k_hmm_scan, dim3(256), dim3(1024),
                               args, 131072, stream);
}

// Round 4
// 631.253 us; speedup vs baseline: 2.7536x; 2.7536x over previous
//
#include <hip/hip_runtime.h>
#include <math.h>

#define Z 512
#define XV 10000
#define SEQ 256
#define NB 64
#define WREG 24               // k-pairs per wave held in registers
#define WLDS 8                // k-pairs per wave held in LDS

typedef _Float16 h2t __attribute__((ext_vector_type(2)));

__device__ __forceinline__ float dot2f(unsigned a, unsigned b, float c) {
#if __has_builtin(__builtin_amdgcn_fdot2)
    return __builtin_amdgcn_fdot2(__builtin_bit_cast(h2t, a), __builtin_bit_cast(h2t, b), c, false);
#else
    h2t av = __builtin_bit_cast(h2t, a), bv = __builtin_bit_cast(h2t, b);
    return fmaf((float)av[0], (float)bv[0], fmaf((float)av[1], (float)bv[1], c));
#endif
}

__device__ __forceinline__ unsigned pack_h2(float a, float b) {
    h2t v; v[0] = (_Float16)a; v[1] = (_Float16)b;
    return __builtin_bit_cast(unsigned, v);
}

__device__ __forceinline__ void online_combine(float& m, float& s, float pm, float ps) {
    if (pm > m) { s = s * __expf(m - pm) + ps; m = pm; }
    else        { s = s + ps * __expf(pm - m); }
}

// ---------------- prep kernels ----------------
__global__ void k_t_collse(const float* __restrict__ T, float* __restrict__ colLSE) {
    __shared__ float ms[256], ss[256];
    const int tid = threadIdx.x;
    const int c0 = blockIdx.x * 64;
    const int cl = tid & 63;
    const int r0 = tid >> 6;
    const int c  = c0 + cl;
    float m = -INFINITY, s = 0.f;
    for (int r = r0; r < Z; r += 4)
        online_combine(m, s, T[(size_t)r * Z + c], 1.f);
    ms[tid] = m; ss[tid] = s;
    __syncthreads();
    if (tid < 128) {
        m = ms[tid]; s = ss[tid];
        online_combine(m, s, ms[tid + 128], ss[tid + 128]);
        ms[tid] = m; ss[tid] = s;
    }
    __syncthreads();
    if (tid < 64) {
        m = ms[tid]; s = ss[tid];
        online_combine(m, s, ms[tid + 64], ss[tid + 64]);
        colLSE[c0 + tid] = m + __logf(s);
    }
}

__global__ void k_emit_part(const float* __restrict__ emit, float2* __restrict__ part) {
    __shared__ float ms[256], ss[256];
    const int tid = threadIdx.x;
    const int g  = blockIdx.x & 7;
    const int rg = blockIdx.x >> 3;
    const int cl = tid & 63;
    const int r0 = tid >> 6;
    const int c  = g * 64 + cl;
    const int rstart = rg * 313;
    const int rend   = (rstart + 313 < XV) ? rstart + 313 : XV;
    float m = -INFINITY, s = 0.f;
    for (int r = rstart + r0; r < rend; r += 4)
        online_combine(m, s, emit[(size_t)r * Z + c], 1.f);
    ms[tid] = m; ss[tid] = s;
    __syncthreads();
    if (tid < 128) {
        m = ms[tid]; s = ss[tid];
        online_combine(m, s, ms[tid + 128], ss[tid + 128]);
        ms[tid] = m; ss[tid] = s;
    }
    __syncthreads();
    if (tid < 64) {
        m = ms[tid]; s = ss[tid];
        online_combine(m, s, ms[tid + 64], ss[tid + 64]);
        part[(size_t)rg * Z + g * 64 + tid] = make_float2(m, s);
    }
}

__global__ void k_finalize(const float2* __restrict__ part, const float* __restrict__ pi,
                           float* __restrict__ emit_lse, float* __restrict__ pi_eff) {
    __shared__ float sm[512];
    const int z = threadIdx.x;
    float m = -INFINITY, s = 0.f;
    for (int rg = 0; rg < 32; ++rg) {
        float2 p = part[(size_t)rg * Z + z];
        online_combine(m, s, p.x, p.y);
    }
    const float el = m + __logf(s);
    emit_lse[z] = el;
    const float v = pi[z];
    sm[z] = v; __syncthreads();
    for (int off = 256; off > 0; off >>= 1) {
        if (z < off) sm[z] = fmaxf(sm[z], sm[z + off]);
        __syncthreads();
    }
    const float mx = sm[0];
    __syncthreads();
    sm[z] = __expf(v - mx); __syncthreads();
    for (int off = 256; off > 0; off >>= 1) {
        if (z < off) sm[z] += sm[z + off];
        __syncthreads();
    }
    const float lse_pi = mx + __logf(sm[0]);
    pi_eff[z] = (v - lse_pi) - el;
}

// Mbuf dword(k, j) = half2(E[2k][j], E[2k+1][j]),  E[i][j] = exp(T_log[j][i] - mT[j])
__global__ void k_build_ET(const float* __restrict__ T, const float* __restrict__ colLSE,
                           const float* __restrict__ emit_lse,
                           _Float16* __restrict__ H, float* __restrict__ adj) {
    __shared__ float sm[256];
    const int j = blockIdx.x, t = threadIdx.x;
    const float v0 = T[(size_t)j * Z + t]       - colLSE[t];
    const float v1 = T[(size_t)j * Z + t + 256] - colLSE[t + 256];
    float m = fmaxf(v0, v1);
    sm[t] = m; __syncthreads();
    for (int off = 128; off > 0; off >>= 1) {
        if (t < off) sm[t] = fmaxf(sm[t], sm[t + off]);
        __syncthreads();
    }
    const float mT = sm[0];
    H[(size_t)(t >> 1) * 1024 + 2 * j + (t & 1)]         = (_Float16)__expf(v0 - mT);
    H[(size_t)((t + 256) >> 1) * 1024 + 2 * j + (t & 1)] = (_Float16)__expf(v1 - mT);
    if (t == 0) adj[j] = mT - emit_lse[j];
}

// ---------------- the scan: 64 blocks (one per batch), 512 threads ----------------
// Matrix fully CU-resident: 192 dwords/thread in VGPRs + 128 KB in LDS.
// Wave w owns i-pairs [32w, 32w+32); thread (w,lane) owns j in {lane+64m}.
// ealpha distribution is wave-local via v_readlane (alpha_i owned by thread i).
__global__ void __launch_bounds__(512, 2)
k_hmm_scan(const int* __restrict__ ids, const float* __restrict__ emit,
           const unsigned* __restrict__ Mbuf, const float* __restrict__ adj,
           const float* __restrict__ pi_eff, float* __restrict__ out) {
    extern __shared__ unsigned dynlds[];
    unsigned* lds_m = dynlds;                    // [8w * WLDS][512] = 32768 dw = 128 KB
    float*    sred  = (float*)(dynlds + 32768);  // [8][512] = 16 KB
    float*    redm  = (float*)(dynlds + 32768 + 4096);  // [8]

    const int b = blockIdx.x;
    const int tid = threadIdx.x;
    const int w = tid >> 6, lane = tid & 63;
    const int kbase = 32 * w;

    // ---- stage matrix: registers (wave-local) ----
    unsigned mreg[WREG * 8];
    #pragma unroll
    for (int kk = 0; kk < WREG; ++kk)
        #pragma unroll
        for (int m = 0; m < 8; ++m)
            mreg[kk * 8 + m] = Mbuf[(size_t)(kbase + kk) * Z + lane + 64 * m];
    // ---- stage matrix: LDS part (wave-local region, no barrier needed) ----
    #pragma unroll
    for (int kk = 0; kk < WLDS; ++kk)
        #pragma unroll
        for (int m = 0; m < 8; ++m)
            lds_m[(w * WLDS + kk) * Z + lane + 64 * m] =
                Mbuf[(size_t)(kbase + WREG + kk) * Z + lane + 64 * m];

    const float adjj = adj[tid];
    float alpha = emit[(size_t)ids[b] * Z + tid] + pi_eff[tid];

    // ---- tail for alpha0: global max -> m_prev, pack ealpha pairs ----
    float m_prev; unsigned pk;
    {
        float mv = alpha;
        #pragma unroll
        for (int off = 32; off > 0; off >>= 1) mv = fmaxf(mv, __shfl_xor(mv, off));
        if (lane == 0) redm[w] = mv;
        __syncthreads();
        float mn = redm[0];
        #pragma unroll
        for (int q = 1; q < 8; ++q) mn = fmaxf(mn, redm[q]);
        m_prev = mn;
        const float e = __expf(alpha - m_prev);
        const float eo = __shfl_xor(e, 1);
        pk = pack_h2(e, eo);                    // meaningful on even lanes only
    }

    for (int t = 1; t < SEQ; ++t) {
        const float obs = emit[(size_t)ids[t * NB + b] * Z + tid];  // early issue

        float sacc[8];
        #pragma unroll
        for (int m = 0; m < 8; ++m) sacc[m] = 0.f;

        // LDS-resident k's first (ds_reads issued early)
        #pragma unroll
        for (int kk = 0; kk < WLDS; ++kk) {
            const unsigned ea =
                (unsigned)__builtin_amdgcn_readlane((int)pk, 2 * (WREG + kk));
            const unsigned* row = lds_m + (w * WLDS + kk) * Z + lane;
            #pragma unroll
            for (int m = 0; m < 8; ++m)
                sacc[m] = dot2f(ea, row[64 * m], sacc[m]);
        }
        // register-resident k's
        #pragma unroll
        for (int kk = 0; kk < WREG; ++kk) {
            const unsigned ea = (unsigned)__builtin_amdgcn_readlane((int)pk, 2 * kk);
            #pragma unroll
            for (int m = 0; m < 8; ++m)
                sacc[m] = dot2f(ea, mreg[kk * 8 + m], sacc[m]);
        }

        // publish partials (single buffer; protected by B2 of previous step)
        #pragma unroll
        for (int m = 0; m < 8; ++m) sred[w * Z + lane + 64 * m] = sacc[m];
        __syncthreads();                         // B1

        float s = 0.f;
        #pragma unroll
        for (int q = 0; q < 8; ++q) s += sred[q * Z + tid];
        alpha = obs + adjj + m_prev + __logf(s);

        float mv = alpha;
        #pragma unroll
        for (int off = 32; off > 0; off >>= 1) mv = fmaxf(mv, __shfl_xor(mv, off));
        if (lane == 0) redm[w] = mv;
        __syncthreads();                         // B2
        float mn = redm[0];
        #pragma unroll
        for (int q = 1; q < 8; ++q) mn = fmaxf(mn, redm[q]);
        m_prev = mn;
        const float e = __expf(alpha - m_prev);
        const float eo = __shfl_xor(e, 1);
        pk = pack_h2(e, eo);
    }

    // ---- final LSE over states ----
    float ev = __expf(alpha - m_prev);
    #pragma unroll
    for (int off = 32; off > 0; off >>= 1) ev += __shfl_xor(ev, off);
    __syncthreads();                             // protect redm reuse
    if (lane == 0) redm[w] = ev;
    __syncthreads();
    if (tid == 0) {
        float tot = 0.f;
        #pragma unroll
        for (int q = 0; q < 8; ++q) tot += redm[q];
        out[b] = -(m_prev + __logf(tot));
    }
}

extern "C" void kernel_launch(void* const* d_in, const int* in_sizes, int n_in,
                              void* d_out, int out_size, void* d_ws, size_t ws_size,
                              hipStream_t stream) {
    const int*   ids  = (const int*)d_in[0];    // [256,64]
    const float* T    = (const float*)d_in[1];  // [512,512]
    const float* pi   = (const float*)d_in[2];  // [512]
    const float* emit = (const float*)d_in[3];  // [10000,512]
    float* out = (float*)d_out;                 // [64]

    float* wsf = (float*)d_ws;
    unsigned* Mbuf   = (unsigned*)wsf;          // 131072 dw = 512 KB fp16 M
    float*  colLSE   = wsf + 131072;
    float*  adj      = wsf + 131584;
    float*  pi_eff   = wsf + 132096;
    float*  emit_lse = wsf + 132608;
    float2* em_part  = (float2*)(wsf + 133120);

    hipLaunchKernelGGL(k_t_collse,  dim3(8),   dim3(256), 0, stream, T, colLSE);
    hipLaunchKernelGGL(k_emit_part, dim3(256), dim3(256), 0, stream, emit, em_part);
    hipLaunchKernelGGL(k_finalize,  dim3(1),   dim3(512), 0, stream, em_part, pi, emit_lse, pi_eff);
    hipLaunchKernelGGL(k_build_ET,  dim3(512), dim3(256), 0, stream, T, colLSE, emit_lse,
                       (_Float16*)Mbuf, adj);

    const int lds_bytes = (32768 + 4096 + 8) * 4;   // 147488 B
    hipFuncSetAttribute((const void*)k_hmm_scan,
                        hipFuncAttributeMaxDynamicSharedMemorySize, lds_bytes);
    hipLaunchKernelGGL(k_hmm_scan, dim3(64), dim3(512), lds_bytes, stream,
                       ids, emit, Mbuf, adj, pi_eff, out);
}

// Round 5
// 513.541 us; speedup vs baseline: 3.3847x; 1.2292x over previous
//
#include <hip/hip_runtime.h>
#include <hip/hip_bf16.h>
#include <math.h>

#define Z 512
#define XV 10000
#define SEQ 256
#define NB 64
#define KT_LDS 4               // k-tiles (K=32 each) staged in LDS
#define KT_TOT 16              // total k-tiles; KT_TOT-KT_LDS live in registers/AGPRs

typedef short bf16x8 __attribute__((ext_vector_type(8)));
typedef float f32x4  __attribute__((ext_vector_type(4)));
typedef unsigned u32x4 __attribute__((ext_vector_type(4)));

__device__ __forceinline__ unsigned short bf16_bits(float a) {
    return __builtin_bit_cast(unsigned short, __float2bfloat16(a));
}
__device__ __forceinline__ unsigned pack_bf2(float a, float b) {
    return ((unsigned)bf16_bits(b) << 16) | (unsigned)bf16_bits(a);
}
__device__ __forceinline__ void online_combine(float& m, float& s, float pm, float ps) {
    if (pm > m) { s = s * __expf(m - pm) + ps; m = pm; }
    else        { s = s + ps * __expf(pm - m); }
}

// ---- prepA: blocks 0..7 = column-LSE of T; blocks 8..263 = emit column-LSE partials
__global__ void k_prepA(const float* __restrict__ T, const float* __restrict__ emit,
                        float* __restrict__ colLSE, float2* __restrict__ em_part) {
    __shared__ float ms[256], ss[256];
    const int tid = threadIdx.x;
    const int cl = tid & 63;
    const int r0 = tid >> 6;
    float m = -INFINITY, s = 0.f;
    int outc;
    if (blockIdx.x < 8) {
        const int c = blockIdx.x * 64 + cl;
        for (int r = r0; r < Z; r += 4)
            online_combine(m, s, T[(size_t)r * Z + c], 1.f);
        outc = 0;
    } else {
        const int bb = blockIdx.x - 8;
        const int g = bb & 7, rg = bb >> 3;
        const int c = g * 64 + cl;
        const int rstart = rg * 313;
        const int rend = (rstart + 313 < XV) ? rstart + 313 : XV;
        for (int r = rstart + r0; r < rend; r += 4)
            online_combine(m, s, emit[(size_t)r * Z + c], 1.f);
        outc = 1;
    }
    ms[tid] = m; ss[tid] = s;
    __syncthreads();
    if (tid < 128) {
        m = ms[tid]; s = ss[tid];
        online_combine(m, s, ms[tid + 128], ss[tid + 128]);
        ms[tid] = m; ss[tid] = s;
    }
    __syncthreads();
    if (tid < 64) {
        m = ms[tid]; s = ss[tid];
        online_combine(m, s, ms[tid + 64], ss[tid + 64]);
        if (outc == 0) {
            colLSE[blockIdx.x * 64 + tid] = m + __logf(s);
        } else {
            const int bb = blockIdx.x - 8;
            em_part[(size_t)(bb >> 3) * Z + (bb & 7) * 64 + tid] = make_float2(m, s);
        }
    }
}

// ---- prepB: blocks 0..511 = build bf16 E-matrix row j (+ mTj); block 512 = finalize
__global__ void k_prepB(const float* __restrict__ T, const float* __restrict__ colLSE,
                        const float2* __restrict__ em_part, const float* __restrict__ pi,
                        unsigned short* __restrict__ H, float* __restrict__ mTj,
                        float* __restrict__ emit_lse, float* __restrict__ pi_eff) {
    __shared__ float sh[512];
    const int tid = threadIdx.x;
    if (blockIdx.x < Z) {
        const int j = blockIdx.x;
        const float v = T[(size_t)j * Z + tid] - colLSE[tid];
        float mv = v;
        #pragma unroll
        for (int off = 32; off > 0; off >>= 1) mv = fmaxf(mv, __shfl_xor(mv, off));
        if ((tid & 63) == 0) sh[tid >> 6] = mv;
        __syncthreads();
        float mT = sh[0];
        #pragma unroll
        for (int q = 1; q < 8; ++q) mT = fmaxf(mT, sh[q]);
        // H dword(k2, j) = bf16pair(E[2k2][j], E[2k2+1][j])
        H[(size_t)(tid >> 1) * 1024 + 2 * j + (tid & 1)] = bf16_bits(__expf(v - mT));
        if (tid == 0) mTj[j] = mT;
    } else {
        const int z = tid;
        float m = -INFINITY, s = 0.f;
        for (int rg = 0; rg < 32; ++rg) {
            float2 p = em_part[(size_t)rg * Z + z];
            online_combine(m, s, p.x, p.y);
        }
        const float el = m + __logf(s);
        emit_lse[z] = el;
        const float v = pi[z];
        sh[z] = v; __syncthreads();
        for (int off = 256; off > 0; off >>= 1) {
            if (z < off) sh[z] = fmaxf(sh[z], sh[z + off]);
            __syncthreads();
        }
        const float mx = sh[0];
        __syncthreads();
        sh[z] = __expf(v - mx); __syncthreads();
        for (int off = 256; off > 0; off >>= 1) {
            if (z < off) sh[z] += sh[z + off];
            __syncthreads();
        }
        pi_eff[z] = (v - (mx + __logf(sh[0]))) - el;
    }
}

// ---- scan: 64 blocks (one batch each), 512 threads, MFMA matvec.
// Wave w owns j-columns [64w, 64w+64) as 4 n-tiles of 16. K=512 as 16 k-tiles of 32.
// B frags: gkt 0..3 in LDS, gkt 4..15 in regs (AGPR-consumed by MFMA).
// A frag = ea broadcast (all 16 rows identical) -> every lane's C is valid.
__global__ void __launch_bounds__(512, 2)
k_hmm_scan(const int* __restrict__ ids, const float* __restrict__ emit,
           const unsigned* __restrict__ Mbuf, const float* __restrict__ mTj,
           const float* __restrict__ emit_lse, const float* __restrict__ pi_eff,
           float* __restrict__ out)
{
    extern __shared__ unsigned dynlds[];
    unsigned* lds_B   = dynlds;                        // 32768 dw = 128 KB
    unsigned* lds_ea  = dynlds + 32768;                // 256 dw
    float*    redm    = (float*)(dynlds + 33024);      // 8
    float*    redf    = (float*)(dynlds + 33032);      // 8
    int*      lds_ids = (int*)(dynlds + 33040);        // 256

    const int b = blockIdx.x;
    const int tid = threadIdx.x;
    const int w = tid >> 6, lane = tid & 63;
    const int g = lane >> 4;                           // k-subgroup 0..3
    const int c = lane & 15;                           // column-in-tile
    const int jbase = 64 * w;

    if (tid < SEQ) lds_ids[tid] = ids[tid * NB + b];

    // ---- stage B: LDS k-tiles (gkt 0..3)
    #pragma unroll
    for (int kt = 0; kt < KT_LDS; ++kt)
        #pragma unroll
        for (int nt = 0; nt < 4; ++nt) {
            const unsigned* src = Mbuf + (size_t)(kt * 16 + g * 4) * Z + jbase + nt * 16 + c;
            u32x4 v = { src[0], src[Z], src[2 * Z], src[3 * Z] };
            *(u32x4*)(lds_B + ((w * KT_LDS + kt) * 4 + nt) * 256 + lane * 4) = v;
        }
    // ---- stage B: register k-tiles (gkt 4..15)
    u32x4 breg[KT_TOT - KT_LDS][4];
    #pragma unroll
    for (int kt = 0; kt < KT_TOT - KT_LDS; ++kt)
        #pragma unroll
        for (int nt = 0; nt < 4; ++nt) {
            const unsigned* src =
                Mbuf + (size_t)((KT_LDS + kt) * 16 + g * 4) * Z + jbase + nt * 16 + c;
            breg[kt][nt] = (u32x4){ src[0], src[Z], src[2 * Z], src[3 * Z] };
        }

    // ---- init alpha: states j = jbase + nt*16 + c (replicated across g-groups)
    const int id0 = ids[b];
    float alpha[4], adjj[4];
    #pragma unroll
    for (int nt = 0; nt < 4; ++nt) {
        const int j = jbase + nt * 16 + c;
        adjj[nt] = mTj[j] - emit_lse[j];
        alpha[nt] = emit[(size_t)id0 * Z + j] + pi_eff[j];
    }
    {
        float mv = fmaxf(fmaxf(alpha[0], alpha[1]), fmaxf(alpha[2], alpha[3]));
        #pragma unroll
        for (int off = 1; off < 16; off <<= 1) mv = fmaxf(mv, __shfl_xor(mv, off));
        if (lane == 0) redm[w] = mv;
    }
    __syncthreads();                                   // lds_B, lds_ids, redm ready

    #pragma unroll 1
    for (int t = 1; t < SEQ; ++t) {
        float m = redm[0];
        #pragma unroll
        for (int q = 1; q < 8; ++q) m = fmaxf(m, redm[q]);

        const int id = lds_ids[t];
        float obs[4];
        #pragma unroll
        for (int nt = 0; nt < 4; ++nt)
            obs[nt] = emit[(size_t)id * Z + jbase + nt * 16 + c];   // early issue

        #pragma unroll
        for (int nt = 0; nt < 4; ++nt) {
            const float e = __expf(alpha[nt] - m);
            const float eo = __shfl_xor(e, 1);
            if (lane < 16 && !(lane & 1))
                lds_ea[32 * w + nt * 8 + (c >> 1)] = pack_bf2(e, eo);
        }
        __syncthreads();                               // B1: ea ready

        f32x4 acc[4] = {{0,0,0,0},{0,0,0,0},{0,0,0,0},{0,0,0,0}};
        #pragma unroll
        for (int kt = 0; kt < KT_TOT; ++kt) {
            const bf16x8 af = __builtin_bit_cast(bf16x8,
                *(const u32x4*)(lds_ea + kt * 16 + g * 4));        // group-broadcast
            if (kt < KT_LDS) {
                #pragma unroll
                for (int nt = 0; nt < 4; ++nt) {
                    const bf16x8 bf = __builtin_bit_cast(bf16x8,
                        *(const u32x4*)(lds_B + ((w * KT_LDS + kt) * 4 + nt) * 256 + lane * 4));
                    acc[nt] = __builtin_amdgcn_mfma_f32_16x16x32_bf16(af, bf, acc[nt], 0, 0, 0);
                }
            } else {
                #pragma unroll
                for (int nt = 0; nt < 4; ++nt)
                    acc[nt] = __builtin_amdgcn_mfma_f32_16x16x32_bf16(af,
                        __builtin_bit_cast(bf16x8, breg[kt - KT_LDS][nt]), acc[nt], 0, 0, 0);
            }
        }

        float mv = -INFINITY;
        #pragma unroll
        for (int nt = 0; nt < 4; ++nt) {
            alpha[nt] = obs[nt] + adjj[nt] + m + __logf(acc[nt][0]);
            mv = fmaxf(mv, alpha[nt]);
        }
        #pragma unroll
        for (int off = 1; off < 16; off <<= 1) mv = fmaxf(mv, __shfl_xor(mv, off));
        if (lane == 0) redm[w] = mv;
        __syncthreads();                               // B2: redm ready, lds_ea free
    }

    // ---- final LSE over all 512 states
    float m = redm[0];
    #pragma unroll
    for (int q = 1; q < 8; ++q) m = fmaxf(m, redm[q]);
    float ev = 0.f;
    #pragma unroll
    for (int nt = 0; nt < 4; ++nt) ev += __expf(alpha[nt] - m);
    #pragma unroll
    for (int off = 1; off < 16; off <<= 1) ev += __shfl_xor(ev, off);
    if (lane == 0) redf[w] = ev;
    __syncthreads();
    if (tid == 0) {
        float tot = 0.f;
        #pragma unroll
        for (int q = 0; q < 8; ++q) tot += redf[q];
        out[b] = -(m + __logf(tot));
    }
}

extern "C" void kernel_launch(void* const* d_in, const int* in_sizes, int n_in,
                              void* d_out, int out_size, void* d_ws, size_t ws_size,
                              hipStream_t stream) {
    const int*   ids  = (const int*)d_in[0];    // [256,64]
    const float* T    = (const float*)d_in[1];  // [512,512]
    const float* pi   = (const float*)d_in[2];  // [512]
    const float* emit = (const float*)d_in[3];  // [10000,512]
    float* out = (float*)d_out;                 // [64]

    float* wsf = (float*)d_ws;
    unsigned* Mbuf   = (unsigned*)wsf;          // 131072 dw = 512 KB bf16 E-matrix
    float*  colLSE   = wsf + 131072;
    float*  mTj      = wsf + 131584;
    float*  pi_eff   = wsf + 132096;
    float*  emit_lse = wsf + 132608;
    float2* em_part  = (float2*)(wsf + 133120); // 32*512 float2

    hipLaunchKernelGGL(k_prepA, dim3(264), dim3(256), 0, stream, T, emit, colLSE, em_part);
    hipLaunchKernelGGL(k_prepB, dim3(513), dim3(512), 0, stream, T, colLSE, em_part, pi,
                       (unsigned short*)Mbuf, mTj, emit_lse, pi_eff);

    const int lds_bytes = 33296 * 4;            // 133184 B
    hipFuncSetAttribute((const void*)k_hmm_scan,
                        hipFuncAttributeMaxDynamicSharedMemorySize, lds_bytes);
    hipLaunchKernelGGL(k_hmm_scan, dim3(64), dim3(512), lds_bytes, stream,
                       ids, emit, Mbuf, mTj, emit_lse, pi_eff, out);
}